// Round 6
// baseline (220.452 us; speedup 1.0000x reference)
//
#include <hip/hip_runtime.h>
#include <hip/hip_fp16.h>
#include <math.h>

// N=50000, E=1600000, F_IN=4, F_OUT=32, T=12
// Buckets of 50 destination nodes: NBKT = 50000/50 = 1000 blocks -> ~4/CU, balanced.
// Pipeline: k_pre -> k_part (1024-bin LDS multi-split + global deg atomics, 250 blocks)
//           -> k_dx (streaming int16 fixed-point x') -> k_acc (512thr/block, 12.9KB LDS,
//              4 blocks/CU: gather + ds_add int accumulate + gates + output).
// R1: float LDS atomicAdd = CAS loop. R3: exec-masked filtering wastes issue BW.
// R4: stranded CUs; int16 cuts per-edge VALU. R5: k_acc is per-CU pipe-bound -> balance
// the per-CU edge load exactly and raise blocks/CU for overlap.
#define CHUNK 6400       // edges per k_part block -> exactly 250 blocks at E=1.6M
#define BK    50         // nodes per bucket
#define NBIN  1024       // scan width (nbkt=1000 <= 1024)
#define CAPG  1920       // per-bucket capacity (mean 1600, sigma ~40 -> +8 sigma)
#define FXS 4096.0f      // 2^12 fixed-point scale
#define FXI 2.44140625e-4f  // 1/4096

// Fold weights (H0=0 => R-gate dead), softmax(att), zero deg[] and gcur[].
__global__ __launch_bounds__(1024) void k_pre(const float* __restrict__ Wz, const float* __restrict__ Lz, const float* __restrict__ lz,
                      const float* __restrict__ Wh, const float* __restrict__ Lh, const float* __restrict__ lh,
                      const float* __restrict__ bz, const float* __restrict__ bh,
                      const float* __restrict__ att,
                      float* __restrict__ AzT, float* __restrict__ AhT,
                      float* __restrict__ bzp, float* __restrict__ bhp, float* __restrict__ probs,
                      int* __restrict__ gcur, int* __restrict__ deg, int n) {
  int t = threadIdx.x;
  int gid = blockIdx.x * 1024 + t;
  if (gid < n) deg[gid] = 0;
  if (blockIdx.x != 0) return;
  gcur[t] = 0;
  if (t < 128) {
    int f = t >> 2, k = t & 3;
    float s = 0.f, s2 = 0.f;
    for (int j = 0; j < 32; ++j) {
      s  = fmaf(Wz[k * 32 + j], Lz[j * 32 + f], s);
      s2 = fmaf(Wh[k * 32 + j], Lh[j * 32 + f], s2);
    }
    AzT[t] = s; AhT[t] = s2;
  }
  if (t >= 128 && t < 160) {
    int f = t - 128;
    float s = lz[f], s2 = lh[f];
    for (int j = 0; j < 32; ++j) {
      s  = fmaf(bz[j], Lz[j * 32 + f], s);
      s2 = fmaf(bh[j], Lh[j * 32 + f], s2);
    }
    bzp[f] = s; bhp[f] = s2;
  }
  if (t == 160) {
    float m = att[0];
    for (int i = 1; i < 12; ++i) m = fmaxf(m, att[i]);
    float e[12]; float s = 0.f;
    for (int i = 0; i < 12; ++i) { e[i] = __expf(att[i] - m); s += e[i]; }
    for (int i = 0; i < 12; ++i) probs[i] = e[i] / s;
  }
}

// LDS multi-split partition into 1000 buckets of 50 nodes + global degree atomics.
// Per block: LDS hist, 1024-bin scan, ONE global atomicAdd per (block,bucket), LDS
// reorder (col re-read from L1-hot chunk), 8-lane-group coalesced flush.
__global__ __launch_bounds__(1024) void k_part(const int* __restrict__ row, const int* __restrict__ col,
                                               int E, int nbkt,
                                               int* __restrict__ gcur, int* __restrict__ deg,
                                               unsigned* __restrict__ part) {
  __shared__ unsigned spak[CHUNK];          // 25.6KB: entries ordered by bucket
  __shared__ int hist[NBIN], sscan[NBIN], scur[NBIN], gbase[NBIN];  // 16KB
  int t = threadIdx.x;
  int base = blockIdx.x * CHUNK;
  int cnt = E - base; if (cnt > CHUNK) cnt = CHUNK;
  hist[t] = 0;
  __syncthreads();
  for (int i = t; i < cnt; i += 1024) {
    int c = col[base + i];
    atomicAdd(&hist[c / BK], 1);
    atomicAdd(&deg[c], 1);
  }
  __syncthreads();
  int v = hist[t];
  sscan[t] = v;
  __syncthreads();
  for (int off = 1; off < NBIN; off <<= 1) {
    int a = 0;
    if (t >= off) a = sscan[t - off];
    __syncthreads();
    sscan[t] += a;
    __syncthreads();
  }
  sscan[t] -= v;                             // exclusive local offset
  gbase[t] = (v > 0) ? atomicAdd(&gcur[t], v) : 0;
  scur[t] = 0;
  __syncthreads();
  for (int i = t; i < cnt; i += 1024) {
    int c = col[base + i];                   // L1-hot re-read (own 25KB chunk)
    int r = row[base + i];
    int b = c / BK, lc = c - b * BK;
    int pos = atomicAdd(&scur[b], 1);
    spak[sscan[b] + pos] = ((unsigned)r << 6) | (unsigned)lc;
  }
  __syncthreads();
  int grp = t >> 3, l8 = t & 7;              // 128 groups of 8 lanes (run len ~6.3)
  for (int b = grp; b < nbkt; b += 128) {
    int len = hist[b], gb = gbase[b], src = sscan[b];
    int lim = CAPG - gb; if (lim > len) lim = len;
    unsigned* dst = part + (size_t)b * CAPG + gb;
    for (int j = l8; j < lim; j += 8) dst[j] = spak[src + j];
  }
}

// Streaming int16 fixed-point x' = round(4096 * rsqrt(deg+1) * x). ~19MB traffic.
__global__ __launch_bounds__(1024) void k_dx(const float4* __restrict__ x4, const int* __restrict__ deg,
                                             uint2* __restrict__ xq, int n12) {
  int gid = blockIdx.x * 1024 + threadIdx.x;
  if (gid < n12) {
    float d = rsqrtf((float)(deg[gid / 12] + 1)) * FXS;   // +1 self loop
    float4 f = x4[gid];
    int a0 = __float2int_rn(d * f.x), a1 = __float2int_rn(d * f.y);
    int a2 = __float2int_rn(d * f.z), a3 = __float2int_rn(d * f.w);
    uint2 u;
    u.x = ((unsigned)a0 & 0xffffu) | ((unsigned)a1 << 16);
    u.y = ((unsigned)a2 & 0xffffu) | ((unsigned)a3 << 16);
    xq[gid] = u;
  }
}

// Fused gather + gates + attention + output. 512 threads per 50-node bucket, 1000 blocks,
// ~12.9KB LDS -> 4 blocks/CU (32 waves). 50x49 int32 LDS accumulator (native ds_add).
// Edge loop: 6 lanes/edge, each lane gathers one uint4 (8 int16) and fires 8 int atomics.
__global__ __launch_bounds__(512) void k_acc(const unsigned* __restrict__ part, const int* __restrict__ gcur,
                                             const int* __restrict__ deg, const uint4* __restrict__ xq4,
                                             const float* __restrict__ AzT, const float* __restrict__ AhT,
                                             const float* __restrict__ bzp, const float* __restrict__ bhp,
                                             const float* __restrict__ probs,
                                             const float* __restrict__ Wo, const float* __restrict__ bo,
                                             float* __restrict__ out, int n) {
  __shared__ int sAcc[BK * 49];                // 9.8KB fixed-point sums; reused as float
  __shared__ float sdi[BK];
  __shared__ float4 sAz4[32], sAh4[32];
  __shared__ float sbzp[32], sbhp[32], sprobs[12], sbo[12], sWo[384];
  int t = threadIdx.x;
  int b = blockIdx.x;
  int nb = b * BK;                             // first node of this bucket

  if (t < 32) {
    sAz4[t] = ((const float4*)AzT)[t];
    sAh4[t] = ((const float4*)AhT)[t];
    sbzp[t] = bzp[t]; sbhp[t] = bhp[t];
  } else if (t < 44) {
    sprobs[t - 32] = probs[t - 32]; sbo[t - 32] = bo[t - 32];
  }
  if (t >= 64 && t < 448) sWo[t - 64] = Wo[t - 64];
  if (t >= 448 && t < 448 + BK) {
    int node = nb + t - 448;
    sdi[t - 448] = (node < n) ? rsqrtf((float)(deg[node] + 1)) : 0.f;
  }
  // self-term init: 50 nodes x 6 lanes x uint4 (8 int16), plain stores
  if (t < BK * 6) {
    int ln = t / 6, cc = t - (t / 6) * 6;
    int node = nb + ln;
    int* ap = sAcc + ln * 49 + cc * 8;
    if (node < n) {
      uint4 v = xq4[(unsigned)node * 6u + cc];
      ap[0] = (int)(short)v.x; ap[1] = (int)v.x >> 16;
      ap[2] = (int)(short)v.y; ap[3] = (int)v.y >> 16;
      ap[4] = (int)(short)v.z; ap[5] = (int)v.z >> 16;
      ap[6] = (int)(short)v.w; ap[7] = (int)v.w >> 16;
    } else {
      ap[0] = 0; ap[1] = 0; ap[2] = 0; ap[3] = 0;
      ap[4] = 0; ap[5] = 0; ap[6] = 0; ap[7] = 0;
    }
  }
  __syncthreads();

  // edge loop over the bucket list, all lanes useful
  int cnt = gcur[b]; if (cnt > CAPG) cnt = CAPG;
  const unsigned* src = part + (size_t)b * CAPG;
  const int NG = 85;                           // 85 groups of 6 lanes (510 threads)
  int g = t / 6, c = t - (t / 6) * 6;
#define PROC(e) { \
    uint4 v = xq4[((e) >> 6) * 6u + (unsigned)c]; \
    int* ap = sAcc + (int)((e) & 63u) * 49 + c * 8; \
    atomicAdd(ap + 0, (int)(short)v.x); atomicAdd(ap + 1, (int)v.x >> 16); \
    atomicAdd(ap + 2, (int)(short)v.y); atomicAdd(ap + 3, (int)v.y >> 16); \
    atomicAdd(ap + 4, (int)(short)v.z); atomicAdd(ap + 5, (int)v.z >> 16); \
    atomicAdd(ap + 6, (int)(short)v.w); atomicAdd(ap + 7, (int)v.w >> 16); \
  }
  if (g < NG) {
    int i = g;
    for (; i + 3 * NG < cnt; i += 4 * NG) {
      unsigned e0 = src[i], e1 = src[i + NG], e2 = src[i + 2 * NG], e3 = src[i + 3 * NG];
      PROC(e0) PROC(e1) PROC(e2) PROC(e3)
    }
    for (; i < cnt; i += NG) { unsigned e = src[i]; PROC(e) }
  }
#undef PROC
  __syncthreads();

  // fixed-point -> float, scaled by destination dinv/4096, in place (5 iterations)
  float* sF = (float*)sAcc;
  for (int k = t; k < BK * 48; k += 512) {
    int ln = k / 48, m = k - ln * 48;
    int idx = ln * 49 + m;
    int raw = sAcc[idx];
    sF[idx] = (float)raw * (sdi[ln] * FXI);
  }
  __syncthreads();

  // gate chain per (node, f): 50*32 = 1600 units, 4 iterations (last masked).
  // Iteration k reads rows [16k,16k+16) slots [0,48), writes slot f (<32) of the same
  // rows after a barrier; later iterations touch strictly higher rows (disjoint).
  for (int k = 0; k < 4; ++k) {
    int u = t + k * 512;
    int ln = u >> 5, f = u & 31;
    bool act = (u < BK * 32) && (nb + ln < n);
    float acc2 = 0.f;
    if (act) {
      const float* y = sF + ln * 49;           // y[m], m = f_in*12 + tt
      float4 az = sAz4[f], ah = sAh4[f];
      float bzf = sbzp[f], bhf = sbhp[f];
#pragma unroll
      for (int tt = 0; tt < 12; ++tt) {
        float y0 = y[tt], y1 = y[12 + tt], y2 = y[24 + tt], y3 = y[36 + tt];
        float za = fmaf(az.x, y0, fmaf(az.y, y1, fmaf(az.z, y2, fmaf(az.w, y3, bzf))));
        float ha = fmaf(ah.x, y0, fmaf(ah.y, y1, fmaf(ah.z, y2, fmaf(ah.w, y3, bhf))));
        float ez = __expf(za);                 // (1 - sigmoid(za)) = 1/(1+ez)
        float ax = fabsf(ha);
        float e2 = __expf(-2.f * ax);
        float gg = (1.f - e2) / ((1.f + ez) * (1.f + e2));  // (1-Z)*tanh(|ha|)
        acc2 = fmaf(sprobs[tt], copysignf(gg, ha), acc2);
      }
    }
    __syncthreads();                           // all reads of these rows done
    if (act) sF[ln * 49 + f] = fmaxf(acc2, 0.f);   // relu(H)
  }
  __syncthreads();

  // output matvec per (node, p): 50*12 = 600 units, 2 iterations
  for (int k = 0; k < 2; ++k) {
    int u = t + k * 512;
    if (u < BK * 12) {
      int ln = u / 12, p = u - (u / 12) * 12;
      int node = nb + ln;
      if (node < n) {
        float s = sbo[p];
        const float* h = sF + ln * 49;
        const float* wv = sWo + p;
#pragma unroll
        for (int f2 = 0; f2 < 32; ++f2) s = fmaf(h[f2], wv[f2 * 12], s);
        out[node * 12 + p] = s;
      }
    }
  }
}

extern "C" void kernel_launch(void* const* d_in, const int* in_sizes, int n_in,
                              void* d_out, int out_size, void* d_ws, size_t ws_size,
                              hipStream_t stream) {
  const float* x   = (const float*)d_in[0];
  const int*   ei  = (const int*)d_in[1];
  const float* att = (const float*)d_in[2];
  const float* Wz  = (const float*)d_in[3];
  const float* bz  = (const float*)d_in[4];
  const float* Lz  = (const float*)d_in[5];
  const float* lz  = (const float*)d_in[6];
  // d_in[7..10] = Wr, br, Lr, lr: dead (H0 == 0 => R unused)
  const float* Wh  = (const float*)d_in[11];
  const float* bh  = (const float*)d_in[12];
  const float* Lh  = (const float*)d_in[13];
  const float* lh  = (const float*)d_in[14];
  const float* Wo  = (const float*)d_in[15];
  const float* bo  = (const float*)d_in[16];
  float* out = (float*)d_out;

  const int N = in_sizes[0] / (4 * 12);
  const int E = in_sizes[1] / 2;
  const int NBKT = (N + BK - 1) / BK;          // 1000 (must be <= NBIN)
  const int* row = ei;
  const int* col = ei + E;

  // workspace carve-up (256B aligned)
  char* w = (char*)d_ws;
  size_t o = 0;
  auto alloc = [&](size_t bytes) -> char* {
    o = (o + 255) & ~(size_t)255;
    char* p = w + o; o += bytes; return p;
  };
  float* pAzT   = (float*)alloc(128 * 4);
  float* pAhT   = (float*)alloc(128 * 4);
  float* pbzp   = (float*)alloc(32 * 4);
  float* pbhp   = (float*)alloc(32 * 4);
  float* pprobs = (float*)alloc(12 * 4);
  int*   pgcur  = (int*)alloc(NBIN * 4);
  int*   pdeg   = (int*)alloc((size_t)N * 4);                      // 200KB
  unsigned* ppart = (unsigned*)alloc((size_t)NBIN * CAPG * 4);     // 7.9MB
  uint2* pxq    = (uint2*)alloc((size_t)N * 12 * 8);               // int16 x', 4.8MB
  (void)ws_size; (void)n_in; (void)out_size;

  k_pre<<<(N + 1023) / 1024, 1024, 0, stream>>>(Wz, Lz, lz, Wh, Lh, lh, bz, bh, att,
                                                pAzT, pAhT, pbzp, pbhp, pprobs, pgcur, pdeg, N);
  k_part<<<(E + CHUNK - 1) / CHUNK, 1024, 0, stream>>>(row, col, E, NBKT, pgcur, pdeg, ppart);
  k_dx<<<(N * 12 + 1023) / 1024, 1024, 0, stream>>>((const float4*)x, pdeg, pxq, N * 12);
  k_acc<<<NBKT, 512, 0, stream>>>(ppart, pgcur, pdeg, (const uint4*)pxq,
                                  pAzT, pAhT, pbzp, pbhp, pprobs,
                                  Wo, bo, out, N);
}

// Round 7
// 186.026 us; speedup vs baseline: 1.1851x; 1.1851x over previous
//
#include <hip/hip_runtime.h>
#include <hip/hip_fp16.h>
#include <math.h>

// N=50000, E=1600000, F_IN=4, F_OUT=32, T=12
// Buckets of 128 destination nodes: NBKT = ceil(N/128) = 391.
// Pipeline: k_pre -> k_part (9-bit LDS multi-split, 250 blocks, proven R5 code)
//           -> k_deg (782 half-bucket blocks: LDS hist -> global deg merge)
//           -> k_dx (streaming int16 fixed-point x')
//           -> k_acc (391 blocks x 1024thr, 28.6KB LDS, proven R5 code, 63.8us).
// R1: float LDS atomicAdd = CAS loop. R3: exec-masked filtering wastes issue BW.
// R4: stranded CUs. R5: k_acc per-CU pipe-bound. R6: fine buckets fragment the
// partition flush into partial-line writes (60MB WRITE_SIZE); change ONE stage at a time.
#define CHUNK 6400       // edges per k_part block -> exactly 250 blocks at E=1.6M
#define CAPG  5120       // per-bucket partition capacity (mean 4096, sigma ~64)
#define BKN   128        // nodes per bucket
#define FXS 4096.0f      // 2^12 fixed-point scale
#define FXI 2.44140625e-4f  // 1/4096

// Fold weights (H0=0 => R-gate dead), softmax(att), zero deg[] and gcur[].
__global__ __launch_bounds__(1024) void k_pre(const float* __restrict__ Wz, const float* __restrict__ Lz, const float* __restrict__ lz,
                      const float* __restrict__ Wh, const float* __restrict__ Lh, const float* __restrict__ lh,
                      const float* __restrict__ bz, const float* __restrict__ bh,
                      const float* __restrict__ att,
                      float* __restrict__ AzT, float* __restrict__ AhT,
                      float* __restrict__ bzp, float* __restrict__ bhp, float* __restrict__ probs,
                      int* __restrict__ gcur, int* __restrict__ deg, int n) {
  int t = threadIdx.x;
  int gid = blockIdx.x * 1024 + t;
  if (gid < n) deg[gid] = 0;
  if (blockIdx.x != 0) return;
  if (t < 512) gcur[t] = 0;
  if (t < 128) {
    int f = t >> 2, k = t & 3;
    float s = 0.f, s2 = 0.f;
    for (int j = 0; j < 32; ++j) {
      s  = fmaf(Wz[k * 32 + j], Lz[j * 32 + f], s);
      s2 = fmaf(Wh[k * 32 + j], Lh[j * 32 + f], s2);
    }
    AzT[t] = s; AhT[t] = s2;
  }
  if (t >= 128 && t < 160) {
    int f = t - 128;
    float s = lz[f], s2 = lh[f];
    for (int j = 0; j < 32; ++j) {
      s  = fmaf(bz[j], Lz[j * 32 + f], s);
      s2 = fmaf(bh[j], Lh[j * 32 + f], s2);
    }
    bzp[f] = s; bhp[f] = s2;
  }
  if (t == 160) {
    float m = att[0];
    for (int i = 1; i < 12; ++i) m = fmaxf(m, att[i]);
    float e[12]; float s = 0.f;
    for (int i = 0; i < 12; ++i) { e[i] = __expf(att[i] - m); s += e[i]; }
    for (int i = 0; i < 12; ++i) probs[i] = e[i] / s;
  }
}

// LDS multi-split partition, 9-bit buckets, 1024 threads/block (EXACT R5 code).
__global__ __launch_bounds__(1024) void k_part(const int* __restrict__ row, const int* __restrict__ col,
                                               int E, int nbkt,
                                               int* __restrict__ gcur, unsigned* __restrict__ part) {
  __shared__ unsigned spak[CHUNK];          // 25.6KB: entries ordered by bucket
  __shared__ unsigned short sbkt[CHUNK];    // 12.5KB
  __shared__ unsigned char slc[CHUNK];      // 6.25KB
  __shared__ int hist[512], sscan[512], scur[512], gbase[512];
  int t = threadIdx.x;
  int base = blockIdx.x * CHUNK;
  int cnt = E - base; if (cnt > CHUNK) cnt = CHUNK;
  if (t < 512) hist[t] = 0;
  __syncthreads();
  for (int i = t; i < cnt; i += 1024) {
    int c = col[base + i];
    int b = c >> 7;
    sbkt[i] = (unsigned short)b;
    slc[i]  = (unsigned char)(c & 127);
    atomicAdd(&hist[b], 1);
  }
  __syncthreads();
  int v = 0;
  if (t < 512) { v = hist[t]; sscan[t] = v; }
  __syncthreads();
  for (int off = 1; off < 512; off <<= 1) {
    int a = 0;
    if (t < 512 && t >= off) a = sscan[t - off];
    __syncthreads();
    if (t < 512) sscan[t] += a;
    __syncthreads();
  }
  if (t < 512) {
    sscan[t] -= v;                             // exclusive local offset
    gbase[t] = (v > 0) ? atomicAdd(&gcur[t], v) : 0;
    scur[t] = 0;
  }
  __syncthreads();
  for (int i = t; i < cnt; i += 1024) {
    int r = row[base + i];
    int b = sbkt[i];
    int pos = atomicAdd(&scur[b], 1);
    spak[sscan[b] + pos] = ((unsigned)r << 7) | (unsigned)slc[i];
  }
  __syncthreads();
  int hw = t >> 5, l32 = t & 31;               // 32 half-waves
  for (int b = hw; b < nbkt; b += 32) {
    int len = hist[b], gb = gbase[b], src = sscan[b];
    int lim = CAPG - gb; if (lim > len) lim = len;
    unsigned* dst = part + (size_t)b * CAPG + gb;
    for (int j = l32; j < lim; j += 32) dst[j] = spak[src + j];
  }
}

// Per-half-bucket degree histogram -> global deg merge. 782 blocks x 256 threads.
__global__ __launch_bounds__(256) void k_deg(const unsigned* __restrict__ part, const int* __restrict__ gcur,
                                             int* __restrict__ deg, int n) {
  __shared__ int hist[BKN];
  int b = blockIdx.x >> 1, half = blockIdx.x & 1, t = threadIdx.x;
  int cnt = gcur[b]; if (cnt > CAPG) cnt = CAPG;
  int s0 = (half * cnt) >> 1, s1 = ((half + 1) * cnt) >> 1;
  const unsigned* src = part + (size_t)b * CAPG;
  if (t < BKN) hist[t] = 0;
  __syncthreads();
  for (int i = s0 + t; i < s1; i += 256) atomicAdd(&hist[src[i] & 127u], 1);
  __syncthreads();
  if (t < BKN) {
    int v = hist[t];
    int node = b * BKN + t;
    if (v > 0 && node < n) atomicAdd(&deg[node], v);
  }
}

// Streaming int16 fixed-point x' = round(4096 * rsqrt(deg+1) * x). ~19MB traffic.
__global__ __launch_bounds__(1024) void k_dx(const float4* __restrict__ x4, const int* __restrict__ deg,
                                             uint2* __restrict__ xq, int n12) {
  int gid = blockIdx.x * 1024 + threadIdx.x;
  if (gid < n12) {
    float d = rsqrtf((float)(deg[gid / 12] + 1)) * FXS;   // +1 self loop
    float4 f = x4[gid];
    int a0 = __float2int_rn(d * f.x), a1 = __float2int_rn(d * f.y);
    int a2 = __float2int_rn(d * f.z), a3 = __float2int_rn(d * f.w);
    uint2 u;
    u.x = ((unsigned)a0 & 0xffffu) | ((unsigned)a1 << 16);
    u.y = ((unsigned)a2 & 0xffffu) | ((unsigned)a3 << 16);
    xq[gid] = u;
  }
}

// Fused gather + gates + attention + output (EXACT R5 code, proven 63.8us;
// sdi recomputed from deg instead of a dinv array). 391 blocks x 1024 threads.
__global__ __launch_bounds__(1024) void k_acc(const unsigned* __restrict__ part, const int* __restrict__ gcur,
                                              const int* __restrict__ deg, const uint4* __restrict__ xq4,
                                              const float* __restrict__ AzT, const float* __restrict__ AhT,
                                              const float* __restrict__ bzp, const float* __restrict__ bhp,
                                              const float* __restrict__ probs,
                                              const float* __restrict__ Wo, const float* __restrict__ bo,
                                              float* __restrict__ out, int n) {
  __shared__ int sAcc[BKN * 49];               // 25KB fixed-point sums; reused as float
  __shared__ float sdi[BKN];
  __shared__ float4 sAz4[32], sAh4[32];
  __shared__ float sbzp[32], sbhp[32], sprobs[12], sbo[12], sWo[384];
  int t = threadIdx.x;
  int b = blockIdx.x;
  int nb = b * BKN;                            // first node of this bucket

  if (t < 32) {
    sAz4[t] = ((const float4*)AzT)[t];
    sAh4[t] = ((const float4*)AhT)[t];
    sbzp[t] = bzp[t]; sbhp[t] = bhp[t];
  }
  if (t >= 32 && t < 44) { sprobs[t - 32] = probs[t - 32]; sbo[t - 32] = bo[t - 32]; }
  if (t >= 64 && t < 448) sWo[t - 64] = Wo[t - 64];
  if (t >= 512 && t < 512 + BKN) {
    int node = nb + t - 512;
    sdi[t - 512] = (node < n) ? rsqrtf((float)(deg[node] + 1)) : 0.f;
  }
  // self-term init: 128 nodes x 6 lanes x uint4 (8 int16), plain stores
  if (t < BKN * 6) {
    int ln = t / 6, cc = t - (t / 6) * 6;
    int node = nb + ln;
    int* ap = sAcc + ln * 49 + cc * 8;
    if (node < n) {
      uint4 v = xq4[(unsigned)node * 6u + cc];
      ap[0] = (int)(short)v.x; ap[1] = (int)v.x >> 16;
      ap[2] = (int)(short)v.y; ap[3] = (int)v.y >> 16;
      ap[4] = (int)(short)v.z; ap[5] = (int)v.z >> 16;
      ap[6] = (int)(short)v.w; ap[7] = (int)v.w >> 16;
    } else {
      ap[0] = 0; ap[1] = 0; ap[2] = 0; ap[3] = 0;
      ap[4] = 0; ap[5] = 0; ap[6] = 0; ap[7] = 0;
    }
  }
  __syncthreads();

  // edge loop over the whole bucket list, all lanes useful
  int cnt = gcur[b]; if (cnt > CAPG) cnt = CAPG;
  const unsigned* src = part + (size_t)b * CAPG;
  const int NG = 170;                          // 170 groups of 6 lanes (1020 threads)
  int g = t / 6, c = t - (t / 6) * 6;
#define PROC(e) { \
    uint4 v = xq4[((e) >> 7) * 6u + (unsigned)c]; \
    int* ap = sAcc + (int)((e) & 127u) * 49 + c * 8; \
    atomicAdd(ap + 0, (int)(short)v.x); atomicAdd(ap + 1, (int)v.x >> 16); \
    atomicAdd(ap + 2, (int)(short)v.y); atomicAdd(ap + 3, (int)v.y >> 16); \
    atomicAdd(ap + 4, (int)(short)v.z); atomicAdd(ap + 5, (int)v.z >> 16); \
    atomicAdd(ap + 6, (int)(short)v.w); atomicAdd(ap + 7, (int)v.w >> 16); \
  }
  if (g < NG) {
    int i = g;
    for (; i + 3 * NG < cnt; i += 4 * NG) {
      unsigned e0 = src[i], e1 = src[i + NG], e2 = src[i + 2 * NG], e3 = src[i + 3 * NG];
      PROC(e0) PROC(e1) PROC(e2) PROC(e3)
    }
    for (; i < cnt; i += NG) { unsigned e = src[i]; PROC(e) }
  }
#undef PROC
  __syncthreads();

  // fixed-point -> float, scaled by destination dinv/4096, in place (6 iterations)
  float* sF = (float*)sAcc;
  for (int k = t; k < BKN * 48; k += 1024) {
    int ln = k / 48, m = k - ln * 48;
    int idx = ln * 49 + m;
    int raw = sAcc[idx];
    sF[idx] = (float)raw * (sdi[ln] * FXI);
  }
  __syncthreads();

  // gate chain per (node, f): 128*32 = 4096 units, 4 exact iterations.
  for (int k = 0; k < 4; ++k) {
    int u = t + k * 1024;
    int ln = u >> 5, f = u & 31;
    bool valid = (nb + ln < n);
    const float* y = sF + ln * 49;             // y[m], m = f_in*12 + tt
    float4 az = sAz4[f], ah = sAh4[f];
    float bzf = sbzp[f], bhf = sbhp[f];
    float acc2 = 0.f;
#pragma unroll
    for (int tt = 0; tt < 12; ++tt) {
      float y0 = y[tt], y1 = y[12 + tt], y2 = y[24 + tt], y3 = y[36 + tt];
      float za = fmaf(az.x, y0, fmaf(az.y, y1, fmaf(az.z, y2, fmaf(az.w, y3, bzf))));
      float ha = fmaf(ah.x, y0, fmaf(ah.y, y1, fmaf(ah.z, y2, fmaf(ah.w, y3, bhf))));
      float ez = __expf(za);                   // (1 - sigmoid(za)) = 1/(1+ez)
      float ax = fabsf(ha);
      float e2 = __expf(-2.f * ax);
      float gg = (1.f - e2) / ((1.f + ez) * (1.f + e2));  // (1-Z)*tanh(|ha|)
      acc2 = fmaf(sprobs[tt], copysignf(gg, ha), acc2);
    }
    __syncthreads();                           // all reads of these rows done
    if (valid) sF[ln * 49 + f] = fmaxf(acc2, 0.f);   // relu(H)
  }
  __syncthreads();

  // output matvec per (node, p): 128*12 = 1536 units, 2 iterations
  for (int k = 0; k < 2; ++k) {
    int u = t + k * 1024;
    if (u < BKN * 12) {
      int ln = u / 12, p = u - (u / 12) * 12;
      int node = nb + ln;
      if (node < n) {
        float s = sbo[p];
        const float* h = sF + ln * 49;
        const float* wv = sWo + p;
#pragma unroll
        for (int f2 = 0; f2 < 32; ++f2) s = fmaf(h[f2], wv[f2 * 12], s);
        out[node * 12 + p] = s;
      }
    }
  }
}

extern "C" void kernel_launch(void* const* d_in, const int* in_sizes, int n_in,
                              void* d_out, int out_size, void* d_ws, size_t ws_size,
                              hipStream_t stream) {
  const float* x   = (const float*)d_in[0];
  const int*   ei  = (const int*)d_in[1];
  const float* att = (const float*)d_in[2];
  const float* Wz  = (const float*)d_in[3];
  const float* bz  = (const float*)d_in[4];
  const float* Lz  = (const float*)d_in[5];
  const float* lz  = (const float*)d_in[6];
  // d_in[7..10] = Wr, br, Lr, lr: dead (H0 == 0 => R unused)
  const float* Wh  = (const float*)d_in[11];
  const float* bh  = (const float*)d_in[12];
  const float* Lh  = (const float*)d_in[13];
  const float* lh  = (const float*)d_in[14];
  const float* Wo  = (const float*)d_in[15];
  const float* bo  = (const float*)d_in[16];
  float* out = (float*)d_out;

  const int N = in_sizes[0] / (4 * 12);
  const int E = in_sizes[1] / 2;
  const int NBKT = (N + BKN - 1) / BKN;        // 391 (must be <= 512)
  const int* row = ei;
  const int* col = ei + E;

  // workspace carve-up (256B aligned)
  char* w = (char*)d_ws;
  size_t o = 0;
  auto alloc = [&](size_t bytes) -> char* {
    o = (o + 255) & ~(size_t)255;
    char* p = w + o; o += bytes; return p;
  };
  float* pAzT   = (float*)alloc(128 * 4);
  float* pAhT   = (float*)alloc(128 * 4);
  float* pbzp   = (float*)alloc(32 * 4);
  float* pbhp   = (float*)alloc(32 * 4);
  float* pprobs = (float*)alloc(12 * 4);
  int*   pgcur  = (int*)alloc(512 * 4);
  int*   pdeg   = (int*)alloc((size_t)N * 4);                      // 200KB
  unsigned* ppart = (unsigned*)alloc((size_t)512 * CAPG * 4);      // 10.5MB
  uint2* pxq    = (uint2*)alloc((size_t)N * 12 * 8);               // int16 x', 4.8MB
  (void)ws_size; (void)n_in; (void)out_size;

  k_pre<<<(N + 1023) / 1024, 1024, 0, stream>>>(Wz, Lz, lz, Wh, Lh, lh, bz, bh, att,
                                                pAzT, pAhT, pbzp, pbhp, pprobs, pgcur, pdeg, N);
  k_part<<<(E + CHUNK - 1) / CHUNK, 1024, 0, stream>>>(row, col, E, NBKT, pgcur, ppart);
  k_deg<<<NBKT * 2, 256, 0, stream>>>(ppart, pgcur, pdeg, N);
  k_dx<<<(N * 12 + 1023) / 1024, 1024, 0, stream>>>((const float4*)x, pdeg, pxq, N * 12);
  k_acc<<<NBKT, 1024, 0, stream>>>(ppart, pgcur, pdeg, (const uint4*)pxq,
                                   pAzT, pAhT, pbzp, pbhp, pprobs,
                                   Wo, bo, out, N);
}

// Round 8
// 180.025 us; speedup vs baseline: 1.2246x; 1.0333x over previous
//
#include <hip/hip_runtime.h>
#include <hip/hip_fp16.h>
#include <math.h>

// N=50000, E=1600000, F_IN=4, F_OUT=32, T=12
// Coarse buckets of 128 dest nodes (NBKT=391) for the partitioner (flush coalescing),
// fine quarters of 32 nodes for the accumulator (occupancy).
// Pipeline: k_pre -> k_part (proven 9-bit multi-split, 250 blocks)
//           -> k_split (per bucket: LDS stage, 4-bin split into contiguous quarter-lists,
//              per-node deg by-product)  -> k_dx (int16 x')
//           -> k_acc (1564 blocks x 256thr, 32-node 6.3KB LDS acc, 24-32 waves/CU).
// R1: float LDS atomicAdd = CAS. R3: exec-mask filtering wastes issue BW. R4: stranded
// CUs. R5/R7: 1024-thr blocks cap at ~1 block/CU (occ 32%) -> latency-exposed gathers.
// R6: fine buckets fragment the partition flush (partial-line writes).
#define CHUNK 6400       // edges per k_part block -> exactly 250 blocks at E=1.6M
#define CAPG  5120       // per-bucket partition capacity (mean 4096, sigma ~64)
#define CAPQ  1280       // per-quarter capacity (mean 1024, sigma ~31 -> +8 sigma)
#define BKN   128        // nodes per coarse bucket
#define BQ    32         // nodes per k_acc quarter
#define FXS 4096.0f      // 2^12 fixed-point scale
#define FXI 2.44140625e-4f  // 1/4096

// Fold weights (H0=0 => R-gate dead), softmax(att), zero gcur[512].
__global__ __launch_bounds__(1024) void k_pre(const float* __restrict__ Wz, const float* __restrict__ Lz, const float* __restrict__ lz,
                      const float* __restrict__ Wh, const float* __restrict__ Lh, const float* __restrict__ lh,
                      const float* __restrict__ bz, const float* __restrict__ bh,
                      const float* __restrict__ att,
                      float* __restrict__ AzT, float* __restrict__ AhT,
                      float* __restrict__ bzp, float* __restrict__ bhp, float* __restrict__ probs,
                      int* __restrict__ gcur) {
  int t = threadIdx.x;
  if (t < 512) gcur[t] = 0;
  if (t < 128) {
    int f = t >> 2, k = t & 3;
    float s = 0.f, s2 = 0.f;
    for (int j = 0; j < 32; ++j) {
      s  = fmaf(Wz[k * 32 + j], Lz[j * 32 + f], s);
      s2 = fmaf(Wh[k * 32 + j], Lh[j * 32 + f], s2);
    }
    AzT[t] = s; AhT[t] = s2;
  }
  if (t >= 128 && t < 160) {
    int f = t - 128;
    float s = lz[f], s2 = lh[f];
    for (int j = 0; j < 32; ++j) {
      s  = fmaf(bz[j], Lz[j * 32 + f], s);
      s2 = fmaf(bh[j], Lh[j * 32 + f], s2);
    }
    bzp[f] = s; bhp[f] = s2;
  }
  if (t == 160) {
    float m = att[0];
    for (int i = 1; i < 12; ++i) m = fmaxf(m, att[i]);
    float e[12]; float s = 0.f;
    for (int i = 0; i < 12; ++i) { e[i] = __expf(att[i] - m); s += e[i]; }
    for (int i = 0; i < 12; ++i) probs[i] = e[i] / s;
  }
}

// LDS multi-split partition, 9-bit buckets, 1024 threads/block (EXACT proven R5/R7 code).
__global__ __launch_bounds__(1024) void k_part(const int* __restrict__ row, const int* __restrict__ col,
                                               int E, int nbkt,
                                               int* __restrict__ gcur, unsigned* __restrict__ part) {
  __shared__ unsigned spak[CHUNK];          // 25.6KB: entries ordered by bucket
  __shared__ unsigned short sbkt[CHUNK];    // 12.5KB
  __shared__ unsigned char slc[CHUNK];      // 6.25KB
  __shared__ int hist[512], sscan[512], scur[512], gbase[512];
  int t = threadIdx.x;
  int base = blockIdx.x * CHUNK;
  int cnt = E - base; if (cnt > CHUNK) cnt = CHUNK;
  if (t < 512) hist[t] = 0;
  __syncthreads();
  for (int i = t; i < cnt; i += 1024) {
    int c = col[base + i];
    int b = c >> 7;
    sbkt[i] = (unsigned short)b;
    slc[i]  = (unsigned char)(c & 127);
    atomicAdd(&hist[b], 1);
  }
  __syncthreads();
  int v = 0;
  if (t < 512) { v = hist[t]; sscan[t] = v; }
  __syncthreads();
  for (int off = 1; off < 512; off <<= 1) {
    int a = 0;
    if (t < 512 && t >= off) a = sscan[t - off];
    __syncthreads();
    if (t < 512) sscan[t] += a;
    __syncthreads();
  }
  if (t < 512) {
    sscan[t] -= v;                             // exclusive local offset
    gbase[t] = (v > 0) ? atomicAdd(&gcur[t], v) : 0;
    scur[t] = 0;
  }
  __syncthreads();
  for (int i = t; i < cnt; i += 1024) {
    int r = row[base + i];
    int b = sbkt[i];
    int pos = atomicAdd(&scur[b], 1);
    spak[sscan[b] + pos] = ((unsigned)r << 7) | (unsigned)slc[i];
  }
  __syncthreads();
  int hw = t >> 5, l32 = t & 31;               // 32 half-waves
  for (int b = hw; b < nbkt; b += 32) {
    int len = hist[b], gb = gbase[b], src = sscan[b];
    int lim = CAPG - gb; if (lim > len) lim = len;
    unsigned* dst = part + (size_t)b * CAPG + gb;
    for (int j = l32; j < lim; j += 32) dst[j] = spak[src + j];
  }
}

// Per-bucket 4-way split by lc>>5 into contiguous quarter-lists + per-node degree.
// One 1024-thread block per bucket. Per-wave cursors limit same-address serialization.
__global__ __launch_bounds__(1024) void k_split(const unsigned* __restrict__ part, const int* __restrict__ gcur,
                                                unsigned* __restrict__ part2, int* __restrict__ qcnt,
                                                int* __restrict__ deg, int n) {
  __shared__ unsigned sedge[CAPG];             // 20.5KB staged entries
  __shared__ int whist[64], wbase[64], hist128[128];
  int b = blockIdx.x, t = threadIdx.x;
  int w = t >> 6;                              // wave id 0..15
  int cnt = gcur[b]; if (cnt > CAPG) cnt = CAPG;
  const unsigned* src = part + (size_t)b * CAPG;
  if (t < 64) whist[t] = 0;
  if (t < 128) hist128[t] = 0;
  __syncthreads();
  for (int i = t; i < cnt; i += 1024) {
    unsigned e = src[i];
    sedge[i] = e;
    int lc = (int)(e & 127u);
    atomicAdd(&hist128[lc], 1);
    atomicAdd(&whist[w * 4 + (lc >> 5)], 1);
  }
  __syncthreads();
  if (t == 0) {
    for (int q = 0; q < 4; ++q) {
      int run = 0;
      for (int ww = 0; ww < 16; ++ww) { wbase[ww * 4 + q] = run; run += whist[ww * 4 + q]; }
      qcnt[b * 4 + q] = (run > CAPQ) ? CAPQ : run;
    }
  }
  __syncthreads();
  if (t < 64) whist[t] = 0;                    // reuse as per-wave cursors
  if (t < 128) {                               // deg: one owner block per bucket
    int node = b * BKN + t;
    if (node < n) deg[node] = hist128[t];
  }
  __syncthreads();
  for (int i = t; i < cnt; i += 1024) {
    unsigned e = sedge[i];
    int q = (int)((e >> 5) & 3u);
    int pos = wbase[w * 4 + q] + atomicAdd(&whist[w * 4 + q], 1);
    if (pos < CAPQ) part2[(size_t)b * CAPG + q * CAPQ + pos] = e;
  }
}

// Streaming int16 fixed-point x' = round(4096 * rsqrt(deg+1) * x). ~19MB traffic.
__global__ __launch_bounds__(1024) void k_dx(const float4* __restrict__ x4, const int* __restrict__ deg,
                                             uint2* __restrict__ xq, int n12) {
  int gid = blockIdx.x * 1024 + threadIdx.x;
  if (gid < n12) {
    float d = rsqrtf((float)(deg[gid / 12] + 1)) * FXS;   // +1 self loop
    float4 f = x4[gid];
    int a0 = __float2int_rn(d * f.x), a1 = __float2int_rn(d * f.y);
    int a2 = __float2int_rn(d * f.z), a3 = __float2int_rn(d * f.w);
    uint2 u;
    u.x = ((unsigned)a0 & 0xffffu) | ((unsigned)a1 << 16);
    u.y = ((unsigned)a2 & 0xffffu) | ((unsigned)a3 << 16);
    xq[gid] = u;
  }
}

// Fused gather + gates + attention + output over a 32-node quarter-list.
// 1564 blocks x 256 threads, ~9.3KB LDS -> 6-8 resident blocks (24-32 waves/CU).
// Edge loop: 6 lanes/edge, uint4 (8 int16) gather + 8 native int LDS atomics.
__global__ __launch_bounds__(256) void k_acc(const unsigned* __restrict__ part2, const int* __restrict__ qcnt,
                                             const int* __restrict__ deg, const uint4* __restrict__ xq4,
                                             const float* __restrict__ AzT, const float* __restrict__ AhT,
                                             const float* __restrict__ bzp, const float* __restrict__ bhp,
                                             const float* __restrict__ probs,
                                             const float* __restrict__ Wo, const float* __restrict__ bo,
                                             float* __restrict__ out, int n) {
  __shared__ int sAcc[BQ * 49];                // 6.3KB fixed-point sums; reused as float
  __shared__ float sdi[BQ];
  __shared__ float4 sAz4[32], sAh4[32];
  __shared__ float sbzp[32], sbhp[32], sprobs[12], sbo[12], sWo[384];
  int t = threadIdx.x;
  int b = blockIdx.x >> 2;                     // coarse bucket
  int q = blockIdx.x & 3;                      // quarter
  int nb = b * BKN + q * BQ;                   // first node of this quarter

  if (t < 32) {
    sAz4[t] = ((const float4*)AzT)[t];
    sAh4[t] = ((const float4*)AhT)[t];
    sbzp[t] = bzp[t]; sbhp[t] = bhp[t];
  } else if (t < 44) {
    sprobs[t - 32] = probs[t - 32]; sbo[t - 32] = bo[t - 32];
  } else if (t < 44 + BQ) {
    int node = nb + t - 44;
    sdi[t - 44] = (node < n) ? rsqrtf((float)(deg[node] + 1)) : 0.f;
  }
  for (int i = t; i < 384; i += 256) sWo[i] = Wo[i];
  // self-term init: 32 nodes x 6 lanes x uint4 (8 int16), plain stores
  if (t < BQ * 6) {
    int ln = t / 6, cc = t - (t / 6) * 6;
    int node = nb + ln;
    int* ap = sAcc + ln * 49 + cc * 8;
    if (node < n) {
      uint4 v = xq4[(unsigned)node * 6u + cc];
      ap[0] = (int)(short)v.x; ap[1] = (int)v.x >> 16;
      ap[2] = (int)(short)v.y; ap[3] = (int)v.y >> 16;
      ap[4] = (int)(short)v.z; ap[5] = (int)v.z >> 16;
      ap[6] = (int)(short)v.w; ap[7] = (int)v.w >> 16;
    } else {
      ap[0] = 0; ap[1] = 0; ap[2] = 0; ap[3] = 0;
      ap[4] = 0; ap[5] = 0; ap[6] = 0; ap[7] = 0;
    }
  }
  __syncthreads();

  // edge loop over this quarter's contiguous sub-list, all lanes useful
  int cnt = qcnt[blockIdx.x];
  const unsigned* src = part2 + (size_t)b * CAPG + q * CAPQ;
  const int NG = 42;                           // 42 groups of 6 lanes (252 threads)
  int g = t / 6, c = t - (t / 6) * 6;
#define PROC(e) { \
    uint4 v = xq4[((e) >> 7) * 6u + (unsigned)c]; \
    int* ap = sAcc + (int)((e) & 31u) * 49 + c * 8; \
    atomicAdd(ap + 0, (int)(short)v.x); atomicAdd(ap + 1, (int)v.x >> 16); \
    atomicAdd(ap + 2, (int)(short)v.y); atomicAdd(ap + 3, (int)v.y >> 16); \
    atomicAdd(ap + 4, (int)(short)v.z); atomicAdd(ap + 5, (int)v.z >> 16); \
    atomicAdd(ap + 6, (int)(short)v.w); atomicAdd(ap + 7, (int)v.w >> 16); \
  }
  if (g < NG) {
    int i = g;
    for (; i + 3 * NG < cnt; i += 4 * NG) {
      unsigned e0 = src[i], e1 = src[i + NG], e2 = src[i + 2 * NG], e3 = src[i + 3 * NG];
      PROC(e0) PROC(e1) PROC(e2) PROC(e3)
    }
    for (; i < cnt; i += NG) { unsigned e = src[i]; PROC(e) }
  }
#undef PROC
  __syncthreads();

  // fixed-point -> float, scaled by destination dinv/4096, in place (6 iterations)
  float* sF = (float*)sAcc;
  for (int k = t; k < BQ * 48; k += 256) {
    int ln = k / 48, m = k - ln * 48;
    int idx = ln * 49 + m;
    int raw = sAcc[idx];
    sF[idx] = (float)raw * (sdi[ln] * FXI);
  }
  __syncthreads();

  // gate chain per (node, f): 32*32 = 1024 units, 4 exact iterations.
  // Iteration k reads rows [8k,8k+8) slots [0,48), writes slot f (<32) of the same rows
  // after a barrier; later iterations touch strictly higher rows (disjoint).
  for (int k = 0; k < 4; ++k) {
    int u = t + k * 256;
    int ln = u >> 5, f = u & 31;
    bool valid = (nb + ln < n);
    const float* y = sF + ln * 49;             // y[m], m = f_in*12 + tt
    float4 az = sAz4[f], ah = sAh4[f];
    float bzf = sbzp[f], bhf = sbhp[f];
    float acc2 = 0.f;
#pragma unroll
    for (int tt = 0; tt < 12; ++tt) {
      float y0 = y[tt], y1 = y[12 + tt], y2 = y[24 + tt], y3 = y[36 + tt];
      float za = fmaf(az.x, y0, fmaf(az.y, y1, fmaf(az.z, y2, fmaf(az.w, y3, bzf))));
      float ha = fmaf(ah.x, y0, fmaf(ah.y, y1, fmaf(ah.z, y2, fmaf(ah.w, y3, bhf))));
      float ez = __expf(za);                   // (1 - sigmoid(za)) = 1/(1+ez)
      float ax = fabsf(ha);
      float e2 = __expf(-2.f * ax);
      float gg = (1.f - e2) / ((1.f + ez) * (1.f + e2));  // (1-Z)*tanh(|ha|)
      acc2 = fmaf(sprobs[tt], copysignf(gg, ha), acc2);
    }
    __syncthreads();                           // all reads of these rows done
    if (valid) sF[ln * 49 + f] = fmaxf(acc2, 0.f);   // relu(H)
  }
  __syncthreads();

  // output matvec per (node, p): 32*12 = 384 units, 2 iterations
  for (int k = 0; k < 2; ++k) {
    int u = t + k * 256;
    if (u < BQ * 12) {
      int ln = u / 12, p = u - (u / 12) * 12;
      int node = nb + ln;
      if (node < n) {
        float s = sbo[p];
        const float* h = sF + ln * 49;
        const float* wv = sWo + p;
#pragma unroll
        for (int f2 = 0; f2 < 32; ++f2) s = fmaf(h[f2], wv[f2 * 12], s);
        out[node * 12 + p] = s;
      }
    }
  }
}

extern "C" void kernel_launch(void* const* d_in, const int* in_sizes, int n_in,
                              void* d_out, int out_size, void* d_ws, size_t ws_size,
                              hipStream_t stream) {
  const float* x   = (const float*)d_in[0];
  const int*   ei  = (const int*)d_in[1];
  const float* att = (const float*)d_in[2];
  const float* Wz  = (const float*)d_in[3];
  const float* bz  = (const float*)d_in[4];
  const float* Lz  = (const float*)d_in[5];
  const float* lz  = (const float*)d_in[6];
  // d_in[7..10] = Wr, br, Lr, lr: dead (H0 == 0 => R unused)
  const float* Wh  = (const float*)d_in[11];
  const float* bh  = (const float*)d_in[12];
  const float* Lh  = (const float*)d_in[13];
  const float* lh  = (const float*)d_in[14];
  const float* Wo  = (const float*)d_in[15];
  const float* bo  = (const float*)d_in[16];
  float* out = (float*)d_out;

  const int N = in_sizes[0] / (4 * 12);
  const int E = in_sizes[1] / 2;
  const int NBKT = (N + BKN - 1) / BKN;        // 391 (must be <= 512)
  const int* row = ei;
  const int* col = ei + E;

  // workspace carve-up (256B aligned)
  char* w = (char*)d_ws;
  size_t o = 0;
  auto alloc = [&](size_t bytes) -> char* {
    o = (o + 255) & ~(size_t)255;
    char* p = w + o; o += bytes; return p;
  };
  float* pAzT   = (float*)alloc(128 * 4);
  float* pAhT   = (float*)alloc(128 * 4);
  float* pbzp   = (float*)alloc(32 * 4);
  float* pbhp   = (float*)alloc(32 * 4);
  float* pprobs = (float*)alloc(12 * 4);
  int*   pgcur  = (int*)alloc(512 * 4);
  int*   pqcnt  = (int*)alloc((size_t)NBKT * 4 * 4);
  int*   pdeg   = (int*)alloc((size_t)N * 4);                      // 200KB
  unsigned* ppart  = (unsigned*)alloc((size_t)512 * CAPG * 4);     // 10.5MB
  unsigned* ppart2 = (unsigned*)alloc((size_t)512 * CAPG * 4);     // 10.5MB
  uint2* pxq    = (uint2*)alloc((size_t)N * 12 * 8);               // int16 x', 4.8MB
  (void)ws_size; (void)n_in; (void)out_size;

  k_pre<<<1, 1024, 0, stream>>>(Wz, Lz, lz, Wh, Lh, lh, bz, bh, att,
                                pAzT, pAhT, pbzp, pbhp, pprobs, pgcur);
  k_part<<<(E + CHUNK - 1) / CHUNK, 1024, 0, stream>>>(row, col, E, NBKT, pgcur, ppart);
  k_split<<<NBKT, 1024, 0, stream>>>(ppart, pgcur, ppart2, pqcnt, pdeg, N);
  k_dx<<<(N * 12 + 1023) / 1024, 1024, 0, stream>>>((const float4*)x, pdeg, pxq, N * 12);
  k_acc<<<NBKT * 4, 256, 0, stream>>>(ppart2, pqcnt, pdeg, (const uint4*)pxq,
                                      pAzT, pAhT, pbzp, pbhp, pprobs,
                                      Wo, bo, out, N);
}